// Round 4
// baseline (37.292 us; speedup 1.0000x reference)
//
#include <hip/hip_runtime.h>

#define NB 32
#define NA 3
#define NT 30
#define NCLS 80
#define NPT 2880            // 3 * NB * NT slots, one wave each
#define NBLK 720            // 4 waves (slots) per 256-thread block

struct __align__(32) BP { double sq, bce, cnt, pad; };

// One fused kernel: per-wave target prep (keys + last-wins dedup + class union),
// cell gather + loss terms, block partial, last-block final reduction.
__global__ __launch_bounds__(256) void yolo_fused(
    const float* __restrict__ o0, const float* __restrict__ o1, const float* __restrict__ o2,
    const float* __restrict__ a0, const float* __restrict__ a1, const float* __restrict__ a2,
    const float* __restrict__ tg,
    unsigned int* __restrict__ counter, BP* __restrict__ parts, float* __restrict__ dout)
{
    const int wid  = threadIdx.x >> 6;
    const int lane = threadIdx.x & 63;
    const int slot = blockIdx.x * 4 + wid;       // 0..2879, never OOB (720*4 = 2880)
    const int sb = slot / NT, t = slot % NT;
    const int s = sb / NB, b = sb % NB;
    const int g = 13 << s;
    const float gf = (float)g;

    const float* ap = (s == 0) ? a0 : (s == 1) ? a1 : a2;
    const float aw0 = ap[0], ah0 = ap[1], aw1 = ap[2], ah1 = ap[3], aw2 = ap[4], ah2 = ap[5];

    // ---- prep: lane i computes cell key for target i of batch b ----
    int key = -1, cls = 0;
    float gx = 0.f, gy = 0.f, gw = 1.f, gh = 1.f;
    if (lane < NT) {
        const float* tp = tg + (size_t)(b * NT + lane) * 5;
        float x0 = tp[0], y0 = tp[1], x1 = tp[2], y1 = tp[3];
        cls = (int)tp[4];
        gx = x0 * gf; gy = y0 * gf;
        gw = fabsf(x1 - x0) * (416.0f * gf);
        gh = fabsf(y1 - y0) * (416.0f * gf);
        int best = 0; float bi = -1.0f;
        { float in0 = fminf(aw0, gw) * fminf(ah0, gh); float u = 1e-8f + aw0 * ah0 + gw * gh - in0; float io = in0 / u; if (io > bi) { bi = io; best = 0; } }
        { float in1 = fminf(aw1, gw) * fminf(ah1, gh); float u = 1e-8f + aw1 * ah1 + gw * gh - in1; float io = in1 / u; if (io > bi) { bi = io; best = 1; } }
        { float in2 = fminf(aw2, gw) * fminf(ah2, gh); float u = 1e-8f + aw2 * ah2 + gw * gh - in2; float io = in2 / u; if (io > bi) { bi = io; best = 2; } }
        key = ((b * NA + best) * g + (int)gx) * g + (int)gy;
    }

    // ---- dedup: last target with same key wins; class union over all matches ----
    const int key_t = __shfl(key, t);
    const unsigned long long m = __ballot(lane < NT && key == key_t);
    const bool win = (m >> (t + 1)) == 0ull;                    // no later target hits this cell
    const unsigned long long mle = m & ((2ull << t) - 1ull);    // matches with index <= t

    unsigned long long lo = 0ull, hi = 0ull;
    if ((mle >> lane) & 1ull) {
        if (cls < 64) lo = 1ull << cls; else hi = 1ull << (cls - 64);
    }
    for (int off = 1; off < 64; off <<= 1) {
        lo |= __shfl_xor(lo, off);
        hi |= __shfl_xor(hi, off);
    }

    // ---- regression targets for slot t (broadcast from lane t) ----
    const float gxt = __shfl(gx, t), gyt = __shfl(gy, t);
    const float gwt = __shfl(gw, t), ght = __shfl(gh, t);
    const int bestt = (key_t / (g * g)) % NA;
    const float awb = (bestt == 0) ? aw0 : (bestt == 1) ? aw1 : aw2;
    const float ahb = (bestt == 0) ? ah0 : (bestt == 1) ? ah1 : ah2;
    const float txv = gxt - floorf(gxt);
    const float tyv = gyt - floorf(gyt);
    const float twv = logf(gwt / awb);
    const float thv = logf(ght / ahb);

    // ---- gather the 85-float cell, accumulate loss terms ----
    double vsq = 0.0, vbce = 0.0;
    if (win) {
        const float* op = (s == 0) ? o0 : (s == 1) ? o1 : o2;
        const float* cell = op + (size_t)key_t * (5 + NCLS);
        {
            float x = cell[lane];                                // elements 0..63
            if (lane < 4) {
                float tv = (lane == 0) ? txv : (lane == 1) ? tyv : (lane == 2) ? twv : thv;
                float d = x - tv;
                vsq = (double)d * d;
            } else if (lane >= 5) {
                int c = lane - 5;                                // classes 0..58
                bool one = (lo >> c) & 1ull;
                float p = fminf(fmaxf(x, 1e-7f), 1.0f - 1e-7f);
                vbce = (double)(one ? -logf(p) : -logf(1.0f - p));
            }
        }
        if (lane < 21) {
            float x = cell[64 + lane];                           // classes 59..79
            int c = 59 + lane;
            bool one = (c < 64) ? ((lo >> c) & 1ull) : ((hi >> (c - 64)) & 1ull);
            float p = fminf(fmaxf(x, 1e-7f), 1.0f - 1e-7f);
            vbce += (double)(one ? -logf(p) : -logf(1.0f - p));
        }
    }
    for (int off = 32; off > 0; off >>= 1) {
        vsq  += __shfl_down(vsq, off);
        vbce += __shfl_down(vbce, off);
    }

    // ---- block partial (all 4 waves same scale: 960 slots/scale, 4 slots/block) ----
    __shared__ double ssq[4], sbce[4];
    __shared__ int    scnt[4];
    __shared__ int    isLast;
    if (lane == 0) { ssq[wid] = vsq; sbce[wid] = vbce; scnt[wid] = win ? 1 : 0; }
    __syncthreads();
    if (threadIdx.x == 0) {
        BP p;
        p.sq  = ssq[0] + ssq[1] + ssq[2] + ssq[3];
        p.bce = sbce[0] + sbce[1] + sbce[2] + sbce[3];
        p.cnt = (double)(scnt[0] + scnt[1] + scnt[2] + scnt[3]);
        p.pad = 0.0;
        parts[blockIdx.x] = p;
        __threadfence();    // release: partial visible at agent scope before count
        unsigned int old = __hip_atomic_fetch_add(counter, 1u, __ATOMIC_ACQ_REL, __HIP_MEMORY_SCOPE_AGENT);
        isLast = (old == NBLK - 1) ? 1 : 0;
    }
    __syncthreads();
    if (!isLast) return;

    // ---- last block: deterministic final reduction over 720 partials ----
    const double* pd = (const double*)parts;
    double fsq[3] = {0, 0, 0}, fbce[3] = {0, 0, 0}, fcnt[3] = {0, 0, 0};
    for (int i = threadIdx.x; i < NBLK; i += 256) {
        // agent-scope atomic loads: read from the coherent point (cross-XCD safe)
        double psq  = __hip_atomic_load(pd + (size_t)i * 4 + 0, __ATOMIC_RELAXED, __HIP_MEMORY_SCOPE_AGENT);
        double pbce = __hip_atomic_load(pd + (size_t)i * 4 + 1, __ATOMIC_RELAXED, __HIP_MEMORY_SCOPE_AGENT);
        double pcnt = __hip_atomic_load(pd + (size_t)i * 4 + 2, __ATOMIC_RELAXED, __HIP_MEMORY_SCOPE_AGENT);
        int sc = i / (NBLK / 3);
        fsq[sc] += psq; fbce[sc] += pbce; fcnt[sc] += pcnt;
    }
    for (int off = 32; off > 0; off >>= 1)
        for (int sc = 0; sc < 3; ++sc) {
            fsq[sc]  += __shfl_down(fsq[sc], off);
            fbce[sc] += __shfl_down(fbce[sc], off);
            fcnt[sc] += __shfl_down(fcnt[sc], off);
        }
    __shared__ double r_sq[4][3], r_bce[4][3], r_cnt[4][3];
    if (lane == 0)
        for (int sc = 0; sc < 3; ++sc) { r_sq[wid][sc] = fsq[sc]; r_bce[wid][sc] = fbce[sc]; r_cnt[wid][sc] = fcnt[sc]; }
    __syncthreads();
    if (threadIdx.x == 0) {
        double loss = 0.0;
        for (int sc = 0; sc < 3; ++sc) {
            double sq = 0.0, bce = 0.0, cn = 0.0;
            for (int w = 0; w < 4; ++w) { sq += r_sq[w][sc]; bce += r_bce[w][sc]; cn += r_cnt[w][sc]; }
            double c = (cn > 0.0) ? cn : 1.0;
            loss += sq / c + bce / (c * (double)NCLS);
        }
        dout[0] = (float)loss;
    }
}

extern "C" void kernel_launch(void* const* d_in, const int* in_sizes, int n_in,
                              void* d_out, int out_size, void* d_ws, size_t ws_size,
                              hipStream_t stream) {
    const float* o0 = (const float*)d_in[0];
    const float* o1 = (const float*)d_in[1];
    const float* o2 = (const float*)d_in[2];
    const float* a0 = (const float*)d_in[3];
    const float* a1 = (const float*)d_in[4];
    const float* a2 = (const float*)d_in[5];
    const float* tg = (const float*)d_in[6];
    float* out = (float*)d_out;

    unsigned int* counter = (unsigned int*)d_ws;
    BP*           parts   = (BP*)((char*)d_ws + 256);   // 720 * 32 B

    hipMemsetAsync(counter, 0, sizeof(unsigned int), stream);   // capturable memset node
    hipLaunchKernelGGL(yolo_fused, dim3(NBLK), dim3(256), 0, stream,
                       o0, o1, o2, a0, a1, a2, tg, counter, parts, out);
}

// Round 5
// 13.151 us; speedup vs baseline: 2.8356x; 2.8356x over previous
//
#include <hip/hip_runtime.h>

#define NB 32
#define NA 3
#define NT 30
#define NCLS 80
#define NPT 2880            // 3 * NB * NT slots, one wave each
#define NBLK 720            // 4 waves (slots) per 256-thread block

struct __align__(32) BP { double sq, bce, cnt, pad; };

// Fused prep + accumulate: per-wave target prep (keys + last-wins dedup +
// class union), cell gather + loss terms, one plain-store partial per block.
__global__ __launch_bounds__(256) void yolo_fused(
    const float* __restrict__ o0, const float* __restrict__ o1, const float* __restrict__ o2,
    const float* __restrict__ a0, const float* __restrict__ a1, const float* __restrict__ a2,
    const float* __restrict__ tg, BP* __restrict__ parts)
{
    const int wid  = threadIdx.x >> 6;
    const int lane = threadIdx.x & 63;
    const int slot = blockIdx.x * 4 + wid;       // 0..2879, never OOB (720*4 = 2880)
    const int sb = slot / NT, t = slot % NT;
    const int s = sb / NB, b = sb % NB;
    const int g = 13 << s;
    const float gf = (float)g;

    const float* ap = (s == 0) ? a0 : (s == 1) ? a1 : a2;
    const float aw0 = ap[0], ah0 = ap[1], aw1 = ap[2], ah1 = ap[3], aw2 = ap[4], ah2 = ap[5];

    // ---- prep: lane i computes cell key for target i of batch b ----
    int key = -1, cls = 0;
    float gx = 0.f, gy = 0.f, gw = 1.f, gh = 1.f;
    if (lane < NT) {
        const float* tp = tg + (size_t)(b * NT + lane) * 5;
        float x0 = tp[0], y0 = tp[1], x1 = tp[2], y1 = tp[3];
        cls = (int)tp[4];
        gx = x0 * gf; gy = y0 * gf;
        gw = fabsf(x1 - x0) * (416.0f * gf);
        gh = fabsf(y1 - y0) * (416.0f * gf);
        int best = 0; float bi = -1.0f;
        { float in0 = fminf(aw0, gw) * fminf(ah0, gh); float u = 1e-8f + aw0 * ah0 + gw * gh - in0; float io = in0 / u; if (io > bi) { bi = io; best = 0; } }
        { float in1 = fminf(aw1, gw) * fminf(ah1, gh); float u = 1e-8f + aw1 * ah1 + gw * gh - in1; float io = in1 / u; if (io > bi) { bi = io; best = 1; } }
        { float in2 = fminf(aw2, gw) * fminf(ah2, gh); float u = 1e-8f + aw2 * ah2 + gw * gh - in2; float io = in2 / u; if (io > bi) { bi = io; best = 2; } }
        key = ((b * NA + best) * g + (int)gx) * g + (int)gy;
    }

    // ---- dedup: last target with same key wins; class union over all matches ----
    const int key_t = __shfl(key, t);
    const unsigned long long m = __ballot(lane < NT && key == key_t);
    const bool win = (m >> (t + 1)) == 0ull;                    // no later target hits this cell
    const unsigned long long mle = m & ((2ull << t) - 1ull);    // matches with index <= t

    unsigned long long lo = 0ull, hi = 0ull;
    if ((mle >> lane) & 1ull) {
        if (cls < 64) lo = 1ull << cls; else hi = 1ull << (cls - 64);
    }
    for (int off = 1; off < 64; off <<= 1) {
        lo |= __shfl_xor(lo, off);
        hi |= __shfl_xor(hi, off);
    }

    // ---- regression targets for slot t (broadcast from lane t) ----
    const float gxt = __shfl(gx, t), gyt = __shfl(gy, t);
    const float gwt = __shfl(gw, t), ght = __shfl(gh, t);
    const int bestt = (key_t / (g * g)) % NA;
    const float awb = (bestt == 0) ? aw0 : (bestt == 1) ? aw1 : aw2;
    const float ahb = (bestt == 0) ? ah0 : (bestt == 1) ? ah1 : ah2;
    const float txv = gxt - floorf(gxt);
    const float tyv = gyt - floorf(gyt);
    const float twv = logf(gwt / awb);
    const float thv = logf(ght / ahb);

    // ---- gather the 85-float cell, accumulate loss terms ----
    double vsq = 0.0, vbce = 0.0;
    if (win) {
        const float* op = (s == 0) ? o0 : (s == 1) ? o1 : o2;
        const float* cell = op + (size_t)key_t * (5 + NCLS);
        {
            float x = cell[lane];                                // elements 0..63
            if (lane < 4) {
                float tv = (lane == 0) ? txv : (lane == 1) ? tyv : (lane == 2) ? twv : thv;
                float d = x - tv;
                vsq = (double)d * d;
            } else if (lane >= 5) {
                int c = lane - 5;                                // classes 0..58
                bool one = (lo >> c) & 1ull;
                float p = fminf(fmaxf(x, 1e-7f), 1.0f - 1e-7f);
                vbce = (double)(one ? -logf(p) : -logf(1.0f - p));
            }
        }
        if (lane < 21) {
            float x = cell[64 + lane];                           // classes 59..79
            int c = 59 + lane;
            bool one = (c < 64) ? ((lo >> c) & 1ull) : ((hi >> (c - 64)) & 1ull);
            float p = fminf(fmaxf(x, 1e-7f), 1.0f - 1e-7f);
            vbce += (double)(one ? -logf(p) : -logf(1.0f - p));
        }
    }
    for (int off = 32; off > 0; off >>= 1) {
        vsq  += __shfl_down(vsq, off);
        vbce += __shfl_down(vbce, off);
    }

    // ---- block partial: plain store, no atomics, no fences ----
    __shared__ double ssq[4], sbce[4];
    __shared__ int    scnt[4];
    if (lane == 0) { ssq[wid] = vsq; sbce[wid] = vbce; scnt[wid] = win ? 1 : 0; }
    __syncthreads();
    if (threadIdx.x == 0) {
        BP p;
        p.sq  = ssq[0] + ssq[1] + ssq[2] + ssq[3];
        p.bce = sbce[0] + sbce[1] + sbce[2] + sbce[3];
        p.cnt = (double)(scnt[0] + scnt[1] + scnt[2] + scnt[3]);
        p.pad = 0.0;
        parts[blockIdx.x] = p;
    }
}

// Final: one block reduces the 720 partials (kernel boundary = full coherence).
// Block b covers slots 4b..4b+3, all in scale b/240 (960 slots per scale).
__global__ __launch_bounds__(256) void yolo_final(
    const BP* __restrict__ parts, float* __restrict__ dout)
{
    const int tid = threadIdx.x;
    const int wid = tid >> 6, lane = tid & 63;

    double fsq[3] = {0, 0, 0}, fbce[3] = {0, 0, 0}, fcnt[3] = {0, 0, 0};
    for (int i = tid; i < NBLK; i += 256) {
        BP p = parts[i];
        int sc = i / (NBLK / 3);
        fsq[sc] += p.sq; fbce[sc] += p.bce; fcnt[sc] += p.cnt;
    }
    for (int off = 32; off > 0; off >>= 1)
        for (int sc = 0; sc < 3; ++sc) {
            fsq[sc]  += __shfl_down(fsq[sc], off);
            fbce[sc] += __shfl_down(fbce[sc], off);
            fcnt[sc] += __shfl_down(fcnt[sc], off);
        }
    __shared__ double r_sq[4][3], r_bce[4][3], r_cnt[4][3];
    if (lane == 0)
        for (int sc = 0; sc < 3; ++sc) { r_sq[wid][sc] = fsq[sc]; r_bce[wid][sc] = fbce[sc]; r_cnt[wid][sc] = fcnt[sc]; }
    __syncthreads();
    if (tid == 0) {
        double loss = 0.0;
        for (int sc = 0; sc < 3; ++sc) {
            double sq = 0.0, bce = 0.0, cn = 0.0;
            for (int w = 0; w < 4; ++w) { sq += r_sq[w][sc]; bce += r_bce[w][sc]; cn += r_cnt[w][sc]; }
            double c = (cn > 0.0) ? cn : 1.0;
            loss += sq / c + bce / (c * (double)NCLS);
        }
        dout[0] = (float)loss;
    }
}

extern "C" void kernel_launch(void* const* d_in, const int* in_sizes, int n_in,
                              void* d_out, int out_size, void* d_ws, size_t ws_size,
                              hipStream_t stream) {
    const float* o0 = (const float*)d_in[0];
    const float* o1 = (const float*)d_in[1];
    const float* o2 = (const float*)d_in[2];
    const float* a0 = (const float*)d_in[3];
    const float* a1 = (const float*)d_in[4];
    const float* a2 = (const float*)d_in[5];
    const float* tg = (const float*)d_in[6];
    float* out = (float*)d_out;

    BP* parts = (BP*)d_ws;      // 720 * 32 B = 23,040 B

    hipLaunchKernelGGL(yolo_fused, dim3(NBLK), dim3(256), 0, stream,
                       o0, o1, o2, a0, a1, a2, tg, parts);
    hipLaunchKernelGGL(yolo_final, dim3(1), dim3(256), 0, stream, parts, out);
}